// Round 15
// baseline (507.287 us; speedup 1.0000x reference)
//
#include <hip/hip_runtime.h>
#include <hip/hip_bf16.h>
#include <math.h>

#define NT 384   // turns
#define TL 384   // per-turn seq len
#define HD 768   // hidden
#define DD 128   // qk proj dim
#define PT_T 86016          // packed P elems per t: 64*64*Sum_{it<6}(it+1)
// packed P layout per t: tile it64 at 2048*it64*(it64+1); chunk32 jc at +jc*2048;
// elem (i_local 0..63, jo 0..31): + i_local*32 + jo.

typedef __attribute__((ext_vector_type(8))) short bf16x8;
typedef __attribute__((ext_vector_type(8))) unsigned short u16x8;
typedef __attribute__((ext_vector_type(4))) float f32x4;

__device__ __forceinline__ unsigned short f2b(float f) {
    union { float f; unsigned int u; } v; v.f = f;
    unsigned int r = v.u + 0x7FFFu + ((v.u >> 16) & 1u);   // RNE
    return (unsigned short)(r >> 16);
}

// ---------------------------------------------------------------------------
// kw_prep: Wt[n][k] = bf16(n<128 ? Wq[k][n] : Wk[k][n-128]); [256][768]
// ---------------------------------------------------------------------------
__global__ __launch_bounds__(256) void kw_prep(
    const float* __restrict__ Wq, const float* __restrict__ Wk,
    unsigned short* __restrict__ Wt)
{
    const int idx = blockIdx.x * 256 + threadIdx.x;     // 0 .. 196607
    const int k = idx >> 8, n = idx & 255;
    const float v = (n < DD) ? Wq[(size_t)k * DD + n] : Wk[(size_t)k * DD + (n - DD)];
    Wt[(size_t)n * HD + k] = f2b(v);
}

// ---------------------------------------------------------------------------
// k_proj: i-major MFMA GEMM + fused xt transpose, with async-STAGE split:
// next k-tile's 16 global fp32 loads issue right after the As-ready barrier,
// hiding HBM latency under MFMA + xt transpose-write (T14 pattern).
// qg/kg epilogue via os2 staging: fully linear 16 KB bursts per array.
// ---------------------------------------------------------------------------
__global__ __launch_bounds__(256, 3) void k_proj(
    const float* __restrict__ x, const unsigned short* __restrict__ Wt,
    const float* __restrict__ bq, const float* __restrict__ bk,
    unsigned short* __restrict__ qg, unsigned short* __restrict__ kg,
    unsigned short* __restrict__ xt)
{
    __shared__ unsigned short As[64 * 64];   // [i][k] bf16, 16B-chunk XOR swizzle
    __shared__ unsigned short os2[64 * 264]; // [i][264]: 0..127 q, 128..255 k, pad 8
    const int tid = threadIdx.x;
    const int lane = tid & 63;
    const int w = tid >> 6;
    const int it6 = blockIdx.x % 6;
    const int t   = blockIdx.x / 6;
    const int i0 = it6 * 64;
    const int n0w = w * 64;
    const int lr = lane & 15;
    const int lg = lane >> 4;

    f32x4 acc[4][4];
    #pragma unroll
    for (int m = 0; m < 4; ++m)
        #pragma unroll
        for (int n = 0; n < 4; ++n) acc[m][n] = (f32x4){0.f, 0.f, 0.f, 0.f};

    const int sm = tid >> 2;           // staging i_local 0..63
    const int sc0 = (tid & 3) * 2;     // staging 16B-chunk pair
    const float* xrow = x + ((size_t)(i0 + sm) * TL + t) * HD + (tid & 3) * 16;

    float4 pf0, pf1, pf2, pf3;         // prefetched 16 fp32 (next k-tile)
    pf0 = *(const float4*)(xrow + 0);
    pf1 = *(const float4*)(xrow + 4);
    pf2 = *(const float4*)(xrow + 8);
    pf3 = *(const float4*)(xrow + 12);

    for (int k0 = 0; k0 < HD; k0 += 64) {
        // convert current tile (already in regs) to bf16
        u16x8 v0, v1;
        v0[0] = f2b(pf0.x); v0[1] = f2b(pf0.y); v0[2] = f2b(pf0.z); v0[3] = f2b(pf0.w);
        v0[4] = f2b(pf1.x); v0[5] = f2b(pf1.y); v0[6] = f2b(pf1.z); v0[7] = f2b(pf1.w);
        v1[0] = f2b(pf2.x); v1[1] = f2b(pf2.y); v1[2] = f2b(pf2.z); v1[3] = f2b(pf2.w);
        v1[4] = f2b(pf3.x); v1[5] = f2b(pf3.y); v1[6] = f2b(pf3.z); v1[7] = f2b(pf3.w);
        __syncthreads();   // previous tile's readers (MFMA + xt) done
        *(u16x8*)&As[sm * 64 + ((sc0     ^ (sm & 7)) * 8)] = v0;
        *(u16x8*)&As[sm * 64 + (((sc0+1) ^ (sm & 7)) * 8)] = v1;
        __syncthreads();   // As ready
        // issue next tile's global loads NOW (hide under MFMA + xt-write)
        if (k0 + 64 < HD) {
            pf0 = *(const float4*)(xrow + k0 + 64);
            pf1 = *(const float4*)(xrow + k0 + 68);
            pf2 = *(const float4*)(xrow + k0 + 72);
            pf3 = *(const float4*)(xrow + k0 + 76);
        }
        #pragma unroll
        for (int kk = 0; kk < 2; ++kk) {
            bf16x8 a[4], b[4];
            #pragma unroll
            for (int m = 0; m < 4; ++m) {
                const int mi = m * 16 + lr;
                const int phys = (lg + kk * 4) ^ (mi & 7);
                a[m] = *(const bf16x8*)&As[mi * 64 + phys * 8];
            }
            #pragma unroll
            for (int n = 0; n < 4; ++n) {
                const int ncol = n0w + n * 16 + lr;
                b[n] = *(const bf16x8*)(Wt + (size_t)ncol * HD + k0 + kk * 32 + lg * 8);
            }
            #pragma unroll
            for (int m = 0; m < 4; ++m)
                #pragma unroll
                for (int n = 0; n < 4; ++n)
                    acc[m][n] = __builtin_amdgcn_mfma_f32_16x16x32_bf16(a[m], b[n], acc[m][n], 0, 0, 0);
        }
        // ---- fused xt transpose-write from As (bit-identical to old k_xt) ----
        #pragma unroll
        for (int uu = 0; uu < 2; ++uu) {
            const int u = uu * 256 + tid;            // 0..511
            const int jc2   = u >> 8;                // 0..1
            const int hl    = (u >> 2) & 63;         // 0..63 -> h = k0+hl
            const int joblk = u & 3;                 // jo base = joblk*8
            u16x8 wv;
            #pragma unroll
            for (int e = 0; e < 8; ++e) {
                const int il = jc2 * 32 + joblk * 8 + e;
                wv[e] = As[il * 64 + (((hl >> 3) ^ (il & 7)) * 8) + (hl & 7)];
            }
            *(u16x8*)&xt[(((size_t)t * 12 + (i0 >> 5) + jc2) * HD + k0 + hl) * 32 + joblk * 8] = wv;
        }
    }
    const float scale = 0.08838834764831845f;   // 1/sqrt(128), folded into q
    __syncthreads();
    // stage epilogue values into LDS
    #pragma unroll
    for (int n = 0; n < 4; ++n) {
        const int ncol = n0w + n * 16 + lr;
        const bool isq = ncol < DD;
        const int d = isq ? ncol : ncol - DD;
        const float bias = isq ? bq[d] : bk[d];
        #pragma unroll
        for (int m = 0; m < 4; ++m)
            #pragma unroll
            for (int r = 0; r < 4; ++r) {
                const int il = m * 16 + lg * 4 + r;
                float v = acc[m][n][r] + bias;
                if (isq) v *= scale;
                os2[il * 264 + ncol] = f2b(v);
            }
    }
    __syncthreads();
    // burst write: fully linear 16 KB per array (i-major rows at fixed t)
    #pragma unroll
    for (int s = 0; s < 8; ++s) {
        const int flat = s * 256 + tid;          // 0..2047
        const int arr  = flat >> 10;             // 0 = q, 1 = k
        const int rem  = flat & 1023;
        const int irow = rem >> 4;
        const int c16  = rem & 15;
        unsigned short* dst = (arr ? kg : qg)
            + ((size_t)t * NT + i0 + irow) * DD + c16 * 8;
        *(u16x8*)dst = *(const u16x8*)&os2[irow * 264 + arr * 128 + c16 * 8];
    }
}

// ---------------------------------------------------------------------------
// k_qk: i-tile 64, 256 threads (4 waves). Per 64-j chunk: 16 MFMA / 4 loads,
// P staged in double-buffered pw (ONE barrier per chunk), then block-wide
// 8 KB linear burst to Pt. + row-sum partials.
// ---------------------------------------------------------------------------
__global__ __launch_bounds__(256, 4) void k_qk(
    const unsigned short* __restrict__ qg, const unsigned short* __restrict__ kg,
    unsigned short* __restrict__ Pt, float* __restrict__ lpart)
{
    __shared__ unsigned short pw[2][4096];   // double-buffered 8 KB P tiles
    __shared__ float red[4][64];
    const int tid = threadIdx.x, lane = tid & 63, w = tid >> 6;
    const int lr = lane & 15, lg = lane >> 4;
    const int bid = blockIdx.x;
    const int lid = (bid & 7) * (2304 / 8) + (bid >> 3);   // XCD-chunk swizzle
    const int it = lid % 6, t = lid / 6;
    const int i0 = it * 64;
    unsigned short* ptile = Pt + (size_t)t * PT_T + 2048 * (size_t)(it * (it + 1));

    bf16x8 aq[4][4];
    #pragma unroll
    for (int m = 0; m < 4; ++m) {
        const unsigned short* qp = qg + ((size_t)t * NT + i0 + m * 16 + lr) * DD + lg * 8;
        #pragma unroll
        for (int kk = 0; kk < 4; ++kk) aq[m][kk] = *(const bf16x8*)(qp + kk * 32);
    }
    float psum[4][4];
    #pragma unroll
    for (int m = 0; m < 4; ++m)
        #pragma unroll
        for (int r = 0; r < 4; ++r) psum[m][r] = 0.f;

    for (int c = 0; c <= it; ++c) {
        const int j0 = c * 64;
        const int pb = c & 1;
        const unsigned short* kp = kg + ((size_t)t * NT + j0 + w * 16 + lr) * DD + lg * 8;
        bf16x8 bk8[4];
        #pragma unroll
        for (int kk = 0; kk < 4; ++kk) bk8[kk] = *(const bf16x8*)(kp + kk * 32);
        const int jg = j0 + w * 16 + lr;
        unsigned short* pws = pw[pb] + (w >> 1) * 2048 + (w & 1) * 16 + lr;
        #pragma unroll
        for (int m = 0; m < 4; ++m) {
            f32x4 s = (f32x4){0.f, 0.f, 0.f, 0.f};
            #pragma unroll
            for (int kk = 0; kk < 4; ++kk)
                s = __builtin_amdgcn_mfma_f32_16x16x32_bf16(aq[m][kk], bk8[kk], s, 0, 0, 0);
            #pragma unroll
            for (int r = 0; r < 4; ++r) {
                const int il = m * 16 + lg * 4 + r;
                const float wv = (jg <= i0 + il) ? __expf(s[r]) : 0.f;
                psum[m][r] += wv;
                pws[il * 32] = f2b(wv);
            }
        }
        __syncthreads();   // pw[pb] fully written (and pw[pb^1] readers done last chunk)
        // block-wide linear burst: 8 KB (chunks 2c, 2c+1) to Pt
        unsigned short* pdst = ptile + (size_t)c * 4096;
        #pragma unroll
        for (int s2 = 0; s2 < 2; ++s2) {
            const int flat = s2 * 256 + tid;
            *(u16x8*)&pdst[flat * 8] = *(const u16x8*)&pw[pb][flat * 8];
        }
    }
    #pragma unroll
    for (int off = 1; off < 16; off <<= 1)
        #pragma unroll
        for (int m = 0; m < 4; ++m)
            #pragma unroll
            for (int r = 0; r < 4; ++r)
                psum[m][r] += __shfl_xor(psum[m][r], off);
    if (lr == 0) {
        #pragma unroll
        for (int m = 0; m < 4; ++m)
            #pragma unroll
            for (int r = 0; r < 4; ++r)
                red[w][m * 16 + lg * 4 + r] = psum[m][r];
    }
    __syncthreads();
    if (tid < 64)
        lpart[(size_t)(i0 + tid) * TL + t] = red[0][tid] + red[1][tid] + red[2][tid] + red[3][tid];
}

// ---------------------------------------------------------------------------
// k_lred: linv[i] = 1 / sum_t lpart[i][t]
// ---------------------------------------------------------------------------
__global__ __launch_bounds__(256) void k_lred(const float* __restrict__ lpart,
                                              float* __restrict__ linv)
{
    const int i = blockIdx.x;
    const int tid = threadIdx.x;
    float s = 0.f;
    for (int t = tid; t < TL; t += 256) s += lpart[(size_t)i * TL + t];
    #pragma unroll
    for (int off = 32; off >= 1; off >>= 1) s += __shfl_down(s, off);
    __shared__ float red[4];
    if ((tid & 63) == 0) red[tid >> 6] = s;
    __syncthreads();
    if (tid == 0) linv[i] = 1.f / (red[0] + red[1] + red[2] + red[3]);
}

// ---------------------------------------------------------------------------
// k_pv_g: i-tile 64 pure GEMM. Block = (t, it64, hb); 4 waves x h-64.
// Per 32-j chunk: 4 Pt A-frags + 4 xt B-frags (2-deep pipelined) + 16 MFMA
// into acc[4][4] (64 AGPR). s_setprio around MFMA clusters. Epilogue in
// two 32-row stages through the 33 KB os buffer, each burst writing full
// 1 KB rows. Row-0 fp32 passthrough folded in.
// ---------------------------------------------------------------------------
__global__ __launch_bounds__(256, 3) void k_pv_g(
    const unsigned short* __restrict__ Pt, const unsigned short* __restrict__ xt,
    const float* __restrict__ linv, const float* __restrict__ x,
    float* __restrict__ out)
{
    __shared__ float os[32 * 260];            // 33,280 B
    const int tid = threadIdx.x, lane = tid & 63, w = tid >> 6;
    const int lr = lane & 15, lg = lane >> 4;
    const int bid = blockIdx.x;               // 0 .. 6911
    const int lid = (bid & 7) * (6912 / 8) + (bid >> 3);
    const int hb  = lid % 3;
    const int rem3 = lid / 3;                 // 0 .. 2303, t-contiguous per XCD
    const int it64 = rem3 % 6, t = rem3 / 6;
    const int i0 = it64 * 64;

    const unsigned short* pbase = Pt + (size_t)t * PT_T + 2048 * (size_t)(it64 * (it64 + 1))
                                + (size_t)lr * 32 + lg * 8;
    const unsigned short* xbase = xt + (((size_t)t * 12) * HD + hb * 256 + w * 64 + lr) * 32 + lg * 8;

    f32x4 acc[4][4];
    #pragma unroll
    for (int m = 0; m < 4; ++m)
        #pragma unroll
        for (int n = 0; n < 4; ++n) acc[m][n] = (f32x4){0.f, 0.f, 0.f, 0.f};

    bf16x8 paA0, paA1, paA2, paA3, bxA0, bxA1, bxA2, bxA3;
    bf16x8 paB0, paB1, paB2, paB3, bxB0, bxB1, bxB2, bxB3;

#define LOADSET(P0, P1, P2, P3, B0, B1, B2, B3, cc) do {                       \
        const unsigned short* pp_ = pbase + (size_t)(cc) * 2048;               \
        P0 = *(const bf16x8*)(pp_);                                            \
        P1 = *(const bf16x8*)(pp_ + 512);                                      \
        P2 = *(const bf16x8*)(pp_ + 1024);                                     \
        P3 = *(const bf16x8*)(pp_ + 1536);                                     \
        const unsigned short* xp_ = xbase + (size_t)(cc) * (HD * 32);          \
        B0 = *(const bf16x8*)(xp_);                                            \
        B1 = *(const bf16x8*)(xp_ + 512);                                      \
        B2 = *(const bf16x8*)(xp_ + 1024);                                     \
        B3 = *(const bf16x8*)(xp_ + 1536);                                     \
    } while (0)

#define MFMASET(P0, P1, P2, P3, B0, B1, B2, B3) do {                           \
        __builtin_amdgcn_s_setprio(1);                                         \
        acc[0][0] = __builtin_amdgcn_mfma_f32_16x16x32_bf16(P0, B0, acc[0][0], 0, 0, 0); \
        acc[1][0] = __builtin_amdgcn_mfma_f32_16x16x32_bf16(P1, B0, acc[1][0], 0, 0, 0); \
        acc[2][0] = __builtin_amdgcn_mfma_f32_16x16x32_bf16(P2, B0, acc[2][0], 0, 0, 0); \
        acc[3][0] = __builtin_amdgcn_mfma_f32_16x16x32_bf16(P3, B0, acc[3][0], 0, 0, 0); \
        acc[0][1] = __builtin_amdgcn_mfma_f32_16x16x32_bf16(P0, B1, acc[0][1], 0, 0, 0); \
        acc[1][1] = __builtin_amdgcn_mfma_f32_16x16x32_bf16(P1, B1, acc[1][1], 0, 0, 0); \
        acc[2][1] = __builtin_amdgcn_mfma_f32_16x16x32_bf16(P2, B1, acc[2][1], 0, 0, 0); \
        acc[3][1] = __builtin_amdgcn_mfma_f32_16x16x32_bf16(P3, B1, acc[3][1], 0, 0, 0); \
        acc[0][2] = __builtin_amdgcn_mfma_f32_16x16x32_bf16(P0, B2, acc[0][2], 0, 0, 0); \
        acc[1][2] = __builtin_amdgcn_mfma_f32_16x16x32_bf16(P1, B2, acc[1][2], 0, 0, 0); \
        acc[2][2] = __builtin_amdgcn_mfma_f32_16x16x32_bf16(P2, B2, acc[2][2], 0, 0, 0); \
        acc[3][2] = __builtin_amdgcn_mfma_f32_16x16x32_bf16(P3, B2, acc[3][2], 0, 0, 0); \
        acc[0][3] = __builtin_amdgcn_mfma_f32_16x16x32_bf16(P0, B3, acc[0][3], 0, 0, 0); \
        acc[1][3] = __builtin_amdgcn_mfma_f32_16x16x32_bf16(P1, B3, acc[1][3], 0, 0, 0); \
        acc[2][3] = __builtin_amdgcn_mfma_f32_16x16x32_bf16(P2, B3, acc[2][3], 0, 0, 0); \
        acc[3][3] = __builtin_amdgcn_mfma_f32_16x16x32_bf16(P3, B3, acc[3][3], 0, 0, 0); \
        __builtin_amdgcn_s_setprio(0);                                         \
    } while (0)

    const int nq = 2 * (it64 + 1);   // always even
    LOADSET(paA0, paA1, paA2, paA3, bxA0, bxA1, bxA2, bxA3, 0);
    for (int c = 0; c < nq; c += 2) {
        LOADSET(paB0, paB1, paB2, paB3, bxB0, bxB1, bxB2, bxB3, c + 1);
        MFMASET(paA0, paA1, paA2, paA3, bxA0, bxA1, bxA2, bxA3);
        if (c + 2 < nq)
            LOADSET(paA0, paA1, paA2, paA3, bxA0, bxA1, bxA2, bxA3, c + 2);
        MFMASET(paB0, paB1, paB2, paB3, bxB0, bxB1, bxB2, bxB3);
    }
#undef LOADSET
#undef MFMASET

    // ---- epilogue: two 32-row stages through os ----
    #pragma unroll
    for (int half = 0; half < 2; ++half) {
        if (half) __syncthreads();   // protect os reuse
        #pragma unroll
        for (int mm = 0; mm < 2; ++mm) {
            const int m = half * 2 + mm;
            #pragma unroll
            for (int r = 0; r < 4; ++r) {
                const int il = mm * 16 + lg * 4 + r;
                const float sc = linv[i0 + half * 32 + il];
                const int hl = w * 64 + lr;
                #pragma unroll
                for (int n = 0; n < 4; ++n)
                    os[il * 260 + hl + n * 16] = acc[m][n][r] * sc;
            }
        }
        __syncthreads();
        #pragma unroll
        for (int s2 = 0; s2 < 8; ++s2) {
            const int flat = s2 * 256 + tid;
            const int gi_l = flat >> 6, rm = flat & 63;
            const int gi = i0 + half * 32 + gi_l;
            float4 v;
            if (gi == 0) v = *(const float4*)&x[(size_t)t * HD + hb * 256 + rm * 4];
            else         v = *(const float4*)&os[gi_l * 260 + rm * 4];
            *(float4*)&out[((size_t)gi * TL + t) * HD + hb * 256 + rm * 4] = v;
        }
    }
}

// ---------------------------------------------------------------------------
// Fallback path (proven round-6): k_stats64 + k_pv3, used if ws too small.
// ---------------------------------------------------------------------------
__global__ __launch_bounds__(256, 4) void k_stats64(
    const unsigned short* __restrict__ qg, const unsigned short* __restrict__ kg,
    float* __restrict__ lpart)
{
    __shared__ float red[4][64];
    const int tid = threadIdx.x, lane = tid & 63, w = tid >> 6;
    const int lr = lane & 15, lg = lane >> 4;
    const int bid = blockIdx.x;
    const int lid = (bid & 7) * (2304 / 8) + (bid >> 3);
    const int it = lid % 6, t = lid / 6;
    const int i0 = it * 64;

    bf16x8 aq[4][4];
    #pragma unroll
    for (int m = 0; m < 4; ++m) {
        const unsigned short* qp = qg + ((size_t)t * NT + i0 + m * 16 + lr) * DD + lg * 8;
        #pragma unroll
        for (int kk = 0; kk < 4; ++kk) aq[m][kk] = *(const bf16x8*)(qp + kk * 32);
    }
    float psum[4][4];
    #pragma unroll
    for (int m = 0; m < 4; ++m)
        #pragma unroll
        for (int r = 0; r < 4; ++r) psum[m][r] = 0.f;

    for (int c = 0; c <= it; ++c) {
        const int j0 = c * 64;
        const unsigned short* kp = kg + ((size_t)t * NT + j0 + w * 16 + lr) * DD + lg * 8;
        bf16x8 bk8[4];
        #pragma unroll
        for (int kk = 0; kk < 4; ++kk) bk8[kk] = *(const bf16x8*)(kp + kk * 32);
        const int jg = j0 + w * 16 + lr;
        #pragma unroll
        for (int m = 0; m < 4; ++m) {
            f32x4 s = (f32x4){0.f, 0.f, 0.f, 0.f};
            #pragma unroll
            for (int kk = 0; kk < 4; ++kk)
                s = __builtin_amdgcn_mfma_f32_16x16x32_bf16(aq[m][kk], bk8[kk], s, 0, 0, 0);
            #pragma unroll
            for (int r = 0; r < 4; ++r) {
                const int ig = i0 + m * 16 + lg * 4 + r;
                psum[m][r] += (jg <= ig) ? __expf(s[r]) : 0.f;
            }
        }
    }
    #pragma unroll
    for (int off = 1; off < 16; off <<= 1)
        #pragma unroll
        for (int m = 0; m < 4; ++m)
            #pragma unroll
            for (int r = 0; r < 4; ++r)
                psum[m][r] += __shfl_xor(psum[m][r], off);
    if (lr == 0) {
        #pragma unroll
        for (int m = 0; m < 4; ++m)
            #pragma unroll
            for (int r = 0; r < 4; ++r)
                red[w][m * 16 + lg * 4 + r] = psum[m][r];
    }
    __syncthreads();
    if (tid < 64)
        lpart[(size_t)(i0 + tid) * TL + t] = red[0][tid] + red[1][tid] + red[2][tid] + red[3][tid];
}

__global__ __launch_bounds__(256, 4) void k_pv3(
    const unsigned short* __restrict__ qg, const unsigned short* __restrict__ kg,
    const unsigned short* __restrict__ xt, const float* __restrict__ linv,
    const float* __restrict__ x, float* __restrict__ out)
{
    __shared__ unsigned short P[32 * 64];
    const int tid = threadIdx.x, lane = tid & 63, w = tid >> 6;
    const int lr = lane & 15, lg = lane >> 4;
    const int bid = blockIdx.x;
    const int lid = (bid & 7) * (4608 / 8) + (bid >> 3);
    const int it = lid % 12, t = lid / 12;
    const int i0 = it * 32;
    const int h0 = blockIdx.y * 256 + w * 64;

    bf16x8 aq[2][4];
    #pragma unroll
    for (int m = 0; m < 2; ++m) {
        const unsigned short* qp = qg + ((size_t)t * NT + i0 + m * 16 + lr) * DD + lg * 8;
        #pragma unroll
        for (int kk = 0; kk < 4; ++kk) aq[m][kk] = *(const bf16x8*)(qp + kk * 32);
    }
    f32x4 acc[2][4];
    #pragma unroll
    for (int m = 0; m < 2; ++m)
        #pragma unroll
        for (int n = 0; n < 4; ++n) acc[m][n] = (f32x4){0.f, 0.f, 0.f, 0.f};

    const int nch = (i0 + 32 + 63) >> 6;
    for (int c = 0; c < nch; ++c) {
        const int j0 = c * 64;
        __syncthreads();
        f32x4 s[2] = { (f32x4){0,0,0,0}, (f32x4){0,0,0,0} };
        const unsigned short* kp = kg + ((size_t)t * NT + j0 + w * 16 + lr) * DD + lg * 8;
        #pragma unroll
        for (int kk = 0; kk < 4; ++kk) {
            const bf16x8 bk8 = *(const bf16x8*)(kp + kk * 32);
            s[0] = __builtin_amdgcn_mfma_f32_16x16x32_bf16(aq[0][kk], bk8, s[0], 0, 0, 0);
            s[1] = __builtin_amdgcn_mfma_f32_16x16x32_bf16(aq[1][kk], bk8, s[1], 0, 0, 0);
        }
        const int jg = j0 + w * 16 + lr;
        const int jl = w * 16 + lr;
        #pragma unroll
        for (int m = 0; m < 2; ++m)
            #pragma unroll
            for (int r = 0; r < 4; ++r) {
                const int il = m * 16 + lg * 4 + r;
                const float wv = (jg <= i0 + il) ? __expf(s[m][r]) : 0.f;
                P[il * 64 + (((jl >> 3) ^ (il & 7)) * 8) + (jl & 7)] = f2b(wv);
            }
        __syncthreads();
        #pragma unroll
        for (int kk2 = 0; kk2 < 2; ++kk2) {
            bf16x8 pa[2];
            #pragma unroll
            for (int m = 0; m < 2; ++m) {
                const int il = m * 16 + lr;
                const int ch = kk2 * 4 + lg;
                pa[m] = *(const bf16x8*)&P[il * 64 + ((ch ^ (il & 7)) * 8)];
            }
            const unsigned short* xp =
                xt + (((size_t)t * 12 + (j0 >> 5) + kk2) * HD + h0 + lr) * 32 + lg * 8;
            #pragma unroll
            for (int n = 0; n < 4; ++n) {
                const bf16x8 bx = *(const bf16x8*)(xp + n * 512);
                acc[0][n] = __builtin_amdgcn_mfma_f32_16x16x32_bf16(pa[0], bx, acc[0][n], 0, 0, 0);
                acc[1][n] = __builtin_amdgcn_mfma_f32_16x16x32_bf16(pa[1], bx, acc[1][n], 0, 0, 0);
            }
        }
    }
    #pragma unroll
    for (int m = 0; m < 2; ++m)
        #pragma unroll
        for (int r = 0; r < 4; ++r) {
            const int gi = i0 + m * 16 + lg * 4 + r;
            float* op = out + ((size_t)gi * TL + t) * HD + h0 + lr;
            if (gi == 0) {
                const float* xp0 = x + (size_t)t * HD + h0 + lr;
                #pragma unroll
                for (int n = 0; n < 4; ++n) op[n * 16] = xp0[n * 16];
            } else {
                const float sc = linv[gi];
                #pragma unroll
                for (int n = 0; n < 4; ++n) op[n * 16] = acc[m][n][r] * sc;
            }
        }
}

extern "C" void kernel_launch(void* const* d_in, const int* in_sizes, int n_in,
                              void* d_out, int out_size, void* d_ws, size_t ws_size,
                              hipStream_t stream)
{
    const float* x  = (const float*)d_in[0];
    const float* Wq = (const float*)d_in[1];
    const float* bq = (const float*)d_in[2];
    const float* Wk = (const float*)d_in[3];
    const float* bk = (const float*)d_in[4];
    float* out = (float*)d_out;

    unsigned short* Wt = (unsigned short*)d_ws;                 // 256*768 bf16
    unsigned short* qb = Wt + (size_t)256 * HD;                 // NT*TL*DD bf16
    unsigned short* kb = qb + (size_t)NT * TL * DD;             // NT*TL*DD bf16
    float* lpart = (float*)(kb + (size_t)NT * TL * DD);         // NT*TL f32
    float* linv  = lpart + (size_t)NT * TL;                     // NT f32
    unsigned short* xt = (unsigned short*)(linv + NT);          // TL*12*HD*32 bf16
    unsigned short* Pt = xt + (size_t)TL * 12 * HD * 32;        // TL*PT_T bf16

    const size_t need = (size_t)((char*)(Pt + (size_t)TL * PT_T) - (char*)d_ws);
    const bool use_split = ws_size >= need;

    kw_prep<<<dim3(768), 256, 0, stream>>>(Wq, Wk, Wt);
    k_proj<<<dim3(NT * TL / 64), 256, 0, stream>>>(x, Wt, bq, bk, qb, kb, xt);
    if (use_split) {
        k_qk<<<dim3(2304), 256, 0, stream>>>(qb, kb, Pt, lpart);
        k_lred<<<dim3(NT), 256, 0, stream>>>(lpart, linv);
        k_pv_g<<<dim3(6912), 256, 0, stream>>>(Pt, xt, linv, x, out);
    } else {
        k_stats64<<<dim3(2304), 256, 0, stream>>>(qb, kb, lpart);
        k_lred<<<dim3(NT), 256, 0, stream>>>(lpart, linv);
        k_pv3<<<dim3(4608, 3), 256, 0, stream>>>(qb, kb, xt, linv, x, out);
    }
}

// Round 16
// 471.939 us; speedup vs baseline: 1.0749x; 1.0749x over previous
//
#include <hip/hip_runtime.h>
#include <hip/hip_bf16.h>
#include <math.h>

#define NT 384   // turns
#define TL 384   // per-turn seq len
#define HD 768   // hidden
#define DD 128   // qk proj dim
#define PT_T 86016          // packed P elems per t: 64*64*Sum_{it<6}(it+1)
// packed P layout per t: tile it64 at 2048*it64*(it64+1); chunk32 jc at +jc*2048;
// elem (i_local 0..63, jo 0..31): + i_local*32 + jo.

typedef __attribute__((ext_vector_type(8))) short bf16x8;
typedef __attribute__((ext_vector_type(8))) unsigned short u16x8;
typedef __attribute__((ext_vector_type(4))) float f32x4;

__device__ __forceinline__ unsigned short f2b(float f) {
    union { float f; unsigned int u; } v; v.f = f;
    unsigned int r = v.u + 0x7FFFu + ((v.u >> 16) & 1u);   // RNE
    return (unsigned short)(r >> 16);
}

// ---------------------------------------------------------------------------
// kw_prep: Wt[n][k] = bf16(n<128 ? Wq[k][n] : Wk[k][n-128]); [256][768]
// ---------------------------------------------------------------------------
__global__ __launch_bounds__(256) void kw_prep(
    const float* __restrict__ Wq, const float* __restrict__ Wk,
    unsigned short* __restrict__ Wt)
{
    const int idx = blockIdx.x * 256 + threadIdx.x;     // 0 .. 196607
    const int k = idx >> 8, n = idx & 255;
    const float v = (n < DD) ? Wq[(size_t)k * DD + n] : Wk[(size_t)k * DD + (n - DD)];
    Wt[(size_t)n * HD + k] = f2b(v);
}

// ---------------------------------------------------------------------------
// k_proj: i-major MFMA GEMM + fused xt transpose.
// Block = (it6, t): 64 turns x 1 t.  Per k-tile: stage bf16(x) in swizzled
// As, MFMA into acc, then transpose-write As -> xt[t][jc][h][jo] (1 KB
// contiguous wave bursts; values bit-identical to the old k_xt).
// qg/kg epilogue via os2 staging: fully linear 16 KB bursts per array.
// ---------------------------------------------------------------------------
__global__ __launch_bounds__(256, 3) void k_proj(
    const float* __restrict__ x, const unsigned short* __restrict__ Wt,
    const float* __restrict__ bq, const float* __restrict__ bk,
    unsigned short* __restrict__ qg, unsigned short* __restrict__ kg,
    unsigned short* __restrict__ xt)
{
    __shared__ unsigned short As[64 * 64];   // [i][k] bf16, 16B-chunk XOR swizzle
    __shared__ unsigned short os2[64 * 264]; // [i][264]: 0..127 q, 128..255 k, pad 8
    const int tid = threadIdx.x;
    const int lane = tid & 63;
    const int w = tid >> 6;
    const int it6 = blockIdx.x % 6;
    const int t   = blockIdx.x / 6;
    const int i0 = it6 * 64;
    const int n0w = w * 64;
    const int lr = lane & 15;
    const int lg = lane >> 4;

    f32x4 acc[4][4];
    #pragma unroll
    for (int m = 0; m < 4; ++m)
        #pragma unroll
        for (int n = 0; n < 4; ++n) acc[m][n] = (f32x4){0.f, 0.f, 0.f, 0.f};

    const int sm = tid >> 2;           // staging i_local 0..63
    const int sc0 = (tid & 3) * 2;     // staging 16B-chunk pair

    for (int k0 = 0; k0 < HD; k0 += 64) {
        __syncthreads();
        {   // stage A tile [64 i][64 k] as bf16, swizzled
            const float* xp = x + ((size_t)(i0 + sm) * TL + t) * HD + k0 + (tid & 3) * 16;
            u16x8 v0, v1;
            #pragma unroll
            for (int u4 = 0; u4 < 2; ++u4) {
                float4 f = *(const float4*)(xp + u4 * 4);
                v0[u4*4+0] = f2b(f.x); v0[u4*4+1] = f2b(f.y);
                v0[u4*4+2] = f2b(f.z); v0[u4*4+3] = f2b(f.w);
            }
            #pragma unroll
            for (int u4 = 0; u4 < 2; ++u4) {
                float4 f = *(const float4*)(xp + 8 + u4 * 4);
                v1[u4*4+0] = f2b(f.x); v1[u4*4+1] = f2b(f.y);
                v1[u4*4+2] = f2b(f.z); v1[u4*4+3] = f2b(f.w);
            }
            *(u16x8*)&As[sm * 64 + ((sc0     ^ (sm & 7)) * 8)] = v0;
            *(u16x8*)&As[sm * 64 + (((sc0+1) ^ (sm & 7)) * 8)] = v1;
        }
        __syncthreads();
        #pragma unroll
        for (int kk = 0; kk < 2; ++kk) {
            bf16x8 a[4], b[4];
            #pragma unroll
            for (int m = 0; m < 4; ++m) {
                const int mi = m * 16 + lr;
                const int phys = (lg + kk * 4) ^ (mi & 7);
                a[m] = *(const bf16x8*)&As[mi * 64 + phys * 8];
            }
            #pragma unroll
            for (int n = 0; n < 4; ++n) {
                const int ncol = n0w + n * 16 + lr;
                b[n] = *(const bf16x8*)(Wt + (size_t)ncol * HD + k0 + kk * 32 + lg * 8);
            }
            #pragma unroll
            for (int m = 0; m < 4; ++m)
                #pragma unroll
                for (int n = 0; n < 4; ++n)
                    acc[m][n] = __builtin_amdgcn_mfma_f32_16x16x32_bf16(a[m], b[n], acc[m][n], 0, 0, 0);
        }
        // ---- fused xt transpose-write from As (bit-identical to old k_xt) ----
        #pragma unroll
        for (int uu = 0; uu < 2; ++uu) {
            const int u = uu * 256 + tid;            // 0..511
            const int jc2   = u >> 8;                // 0..1
            const int hl    = (u >> 2) & 63;         // 0..63 -> h = k0+hl
            const int joblk = u & 3;                 // jo base = joblk*8
            u16x8 wv;
            #pragma unroll
            for (int e = 0; e < 8; ++e) {
                const int il = jc2 * 32 + joblk * 8 + e;
                wv[e] = As[il * 64 + (((hl >> 3) ^ (il & 7)) * 8) + (hl & 7)];
            }
            *(u16x8*)&xt[(((size_t)t * 12 + (i0 >> 5) + jc2) * HD + k0 + hl) * 32 + joblk * 8] = wv;
        }
    }
    const float scale = 0.08838834764831845f;   // 1/sqrt(128), folded into q
    __syncthreads();
    // stage epilogue values into LDS
    #pragma unroll
    for (int n = 0; n < 4; ++n) {
        const int ncol = n0w + n * 16 + lr;
        const bool isq = ncol < DD;
        const int d = isq ? ncol : ncol - DD;
        const float bias = isq ? bq[d] : bk[d];
        #pragma unroll
        for (int m = 0; m < 4; ++m)
            #pragma unroll
            for (int r = 0; r < 4; ++r) {
                const int il = m * 16 + lg * 4 + r;
                float v = acc[m][n][r] + bias;
                if (isq) v *= scale;
                os2[il * 264 + ncol] = f2b(v);
            }
    }
    __syncthreads();
    // burst write: fully linear 16 KB per array (i-major rows at fixed t)
    #pragma unroll
    for (int s = 0; s < 8; ++s) {
        const int flat = s * 256 + tid;          // 0..2047
        const int arr  = flat >> 10;             // 0 = q, 1 = k
        const int rem  = flat & 1023;
        const int irow = rem >> 4;
        const int c16  = rem & 15;
        unsigned short* dst = (arr ? kg : qg)
            + ((size_t)t * NT + i0 + irow) * DD + c16 * 8;
        *(u16x8*)dst = *(const u16x8*)&os2[irow * 264 + arr * 128 + c16 * 8];
    }
}

// ---------------------------------------------------------------------------
// k_qk: i-tile 64, 256 threads (4 waves). Per 64-j chunk: wave w owns
// j-slice w*16, computes S for all 4 m-tiles (16 MFMA / 4 loads),
// P = mask?exp(s):0 staged in LDS, then block-wide 8 KB linear burst to Pt
// (1 KB contiguous per wave-instruction, full sectors). + row-sum partials.
// ---------------------------------------------------------------------------
__global__ __launch_bounds__(256, 4) void k_qk(
    const unsigned short* __restrict__ qg, const unsigned short* __restrict__ kg,
    unsigned short* __restrict__ Pt, float* __restrict__ lpart)
{
    __shared__ unsigned short pw[4096];   // [2 jc][64 i][32 jo] bf16 = 8 KB
    __shared__ float red[4][64];
    const int tid = threadIdx.x, lane = tid & 63, w = tid >> 6;
    const int lr = lane & 15, lg = lane >> 4;
    const int bid = blockIdx.x;
    const int lid = (bid & 7) * (2304 / 8) + (bid >> 3);   // XCD-chunk swizzle
    const int it = lid % 6, t = lid / 6;
    const int i0 = it * 64;
    unsigned short* ptile = Pt + (size_t)t * PT_T + 2048 * (size_t)(it * (it + 1));

    bf16x8 aq[4][4];
    #pragma unroll
    for (int m = 0; m < 4; ++m) {
        const unsigned short* qp = qg + ((size_t)t * NT + i0 + m * 16 + lr) * DD + lg * 8;
        #pragma unroll
        for (int kk = 0; kk < 4; ++kk) aq[m][kk] = *(const bf16x8*)(qp + kk * 32);
    }
    float psum[4][4];
    #pragma unroll
    for (int m = 0; m < 4; ++m)
        #pragma unroll
        for (int r = 0; r < 4; ++r) psum[m][r] = 0.f;

    for (int c = 0; c <= it; ++c) {
        const int j0 = c * 64;
        const unsigned short* kp = kg + ((size_t)t * NT + j0 + w * 16 + lr) * DD + lg * 8;
        bf16x8 bk8[4];
        #pragma unroll
        for (int kk = 0; kk < 4; ++kk) bk8[kk] = *(const bf16x8*)(kp + kk * 32);
        const int jg = j0 + w * 16 + lr;
        unsigned short* pws = pw + (w >> 1) * 2048 + (w & 1) * 16 + lr;
        #pragma unroll
        for (int m = 0; m < 4; ++m) {
            f32x4 s = (f32x4){0.f, 0.f, 0.f, 0.f};
            #pragma unroll
            for (int kk = 0; kk < 4; ++kk)
                s = __builtin_amdgcn_mfma_f32_16x16x32_bf16(aq[m][kk], bk8[kk], s, 0, 0, 0);
            #pragma unroll
            for (int r = 0; r < 4; ++r) {
                const int il = m * 16 + lg * 4 + r;
                const float wv = (jg <= i0 + il) ? __expf(s[r]) : 0.f;
                psum[m][r] += wv;
                pws[il * 32] = f2b(wv);
            }
        }
        __syncthreads();
        // block-wide linear burst: 8 KB (chunks 2c, 2c+1) to Pt
        unsigned short* pdst = ptile + (size_t)c * 4096;
        #pragma unroll
        for (int s2 = 0; s2 < 2; ++s2) {
            const int flat = s2 * 256 + tid;
            *(u16x8*)&pdst[flat * 8] = *(const u16x8*)&pw[flat * 8];
        }
        __syncthreads();
    }
    #pragma unroll
    for (int off = 1; off < 16; off <<= 1)
        #pragma unroll
        for (int m = 0; m < 4; ++m)
            #pragma unroll
            for (int r = 0; r < 4; ++r)
                psum[m][r] += __shfl_xor(psum[m][r], off);
    if (lr == 0) {
        #pragma unroll
        for (int m = 0; m < 4; ++m)
            #pragma unroll
            for (int r = 0; r < 4; ++r)
                red[w][m * 16 + lg * 4 + r] = psum[m][r];
    }
    __syncthreads();
    if (tid < 64)
        lpart[(size_t)(i0 + tid) * TL + t] = red[0][tid] + red[1][tid] + red[2][tid] + red[3][tid];
}

// ---------------------------------------------------------------------------
// k_lred: linv[i] = 1 / sum_t lpart[i][t]
// ---------------------------------------------------------------------------
__global__ __launch_bounds__(256) void k_lred(const float* __restrict__ lpart,
                                              float* __restrict__ linv)
{
    const int i = blockIdx.x;
    const int tid = threadIdx.x;
    float s = 0.f;
    for (int t = tid; t < TL; t += 256) s += lpart[(size_t)i * TL + t];
    #pragma unroll
    for (int off = 32; off >= 1; off >>= 1) s += __shfl_down(s, off);
    __shared__ float red[4];
    if ((tid & 63) == 0) red[tid >> 6] = s;
    __syncthreads();
    if (tid == 0) linv[i] = 1.f / (red[0] + red[1] + red[2] + red[3]);
}

// ---------------------------------------------------------------------------
// k_pv_g: i-tile 64 pure GEMM. Block = (t, it64, hb); 4 waves x h-64.
// Per 32-j chunk: 4 Pt A-frags + 4 xt B-frags (2-deep pipelined) + 16 MFMA
// into acc[4][4] (64 AGPR). s_setprio around MFMA clusters. Epilogue in
// two 32-row stages through the 33 KB os buffer, each burst writing full
// 1 KB rows. Row-0 fp32 passthrough folded in.
// ---------------------------------------------------------------------------
__global__ __launch_bounds__(256, 3) void k_pv_g(
    const unsigned short* __restrict__ Pt, const unsigned short* __restrict__ xt,
    const float* __restrict__ linv, const float* __restrict__ x,
    float* __restrict__ out)
{
    __shared__ float os[32 * 260];            // 33,280 B
    const int tid = threadIdx.x, lane = tid & 63, w = tid >> 6;
    const int lr = lane & 15, lg = lane >> 4;
    const int bid = blockIdx.x;               // 0 .. 6911
    const int lid = (bid & 7) * (6912 / 8) + (bid >> 3);
    const int hb  = lid % 3;
    const int rem3 = lid / 3;                 // 0 .. 2303, t-contiguous per XCD
    const int it64 = rem3 % 6, t = rem3 / 6;
    const int i0 = it64 * 64;

    const unsigned short* pbase = Pt + (size_t)t * PT_T + 2048 * (size_t)(it64 * (it64 + 1))
                                + (size_t)lr * 32 + lg * 8;
    const unsigned short* xbase = xt + (((size_t)t * 12) * HD + hb * 256 + w * 64 + lr) * 32 + lg * 8;

    f32x4 acc[4][4];
    #pragma unroll
    for (int m = 0; m < 4; ++m)
        #pragma unroll
        for (int n = 0; n < 4; ++n) acc[m][n] = (f32x4){0.f, 0.f, 0.f, 0.f};

    bf16x8 paA0, paA1, paA2, paA3, bxA0, bxA1, bxA2, bxA3;
    bf16x8 paB0, paB1, paB2, paB3, bxB0, bxB1, bxB2, bxB3;

#define LOADSET(P0, P1, P2, P3, B0, B1, B2, B3, cc) do {                       \
        const unsigned short* pp_ = pbase + (size_t)(cc) * 2048;               \
        P0 = *(const bf16x8*)(pp_);                                            \
        P1 = *(const bf16x8*)(pp_ + 512);                                      \
        P2 = *(const bf16x8*)(pp_ + 1024);                                     \
        P3 = *(const bf16x8*)(pp_ + 1536);                                     \
        const unsigned short* xp_ = xbase + (size_t)(cc) * (HD * 32);          \
        B0 = *(const bf16x8*)(xp_);                                            \
        B1 = *(const bf16x8*)(xp_ + 512);                                      \
        B2 = *(const bf16x8*)(xp_ + 1024);                                     \
        B3 = *(const bf16x8*)(xp_ + 1536);                                     \
    } while (0)

#define MFMASET(P0, P1, P2, P3, B0, B1, B2, B3) do {                           \
        __builtin_amdgcn_s_setprio(1);                                         \
        acc[0][0] = __builtin_amdgcn_mfma_f32_16x16x32_bf16(P0, B0, acc[0][0], 0, 0, 0); \
        acc[1][0] = __builtin_amdgcn_mfma_f32_16x16x32_bf16(P1, B0, acc[1][0], 0, 0, 0); \
        acc[2][0] = __builtin_amdgcn_mfma_f32_16x16x32_bf16(P2, B0, acc[2][0], 0, 0, 0); \
        acc[3][0] = __builtin_amdgcn_mfma_f32_16x16x32_bf16(P3, B0, acc[3][0], 0, 0, 0); \
        acc[0][1] = __builtin_amdgcn_mfma_f32_16x16x32_bf16(P0, B1, acc[0][1], 0, 0, 0); \
        acc[1][1] = __builtin_amdgcn_mfma_f32_16x16x32_bf16(P1, B1, acc[1][1], 0, 0, 0); \
        acc[2][1] = __builtin_amdgcn_mfma_f32_16x16x32_bf16(P2, B1, acc[2][1], 0, 0, 0); \
        acc[3][1] = __builtin_amdgcn_mfma_f32_16x16x32_bf16(P3, B1, acc[3][1], 0, 0, 0); \
        acc[0][2] = __builtin_amdgcn_mfma_f32_16x16x32_bf16(P0, B2, acc[0][2], 0, 0, 0); \
        acc[1][2] = __builtin_amdgcn_mfma_f32_16x16x32_bf16(P1, B2, acc[1][2], 0, 0, 0); \
        acc[2][2] = __builtin_amdgcn_mfma_f32_16x16x32_bf16(P2, B2, acc[2][2], 0, 0, 0); \
        acc[3][2] = __builtin_amdgcn_mfma_f32_16x16x32_bf16(P3, B2, acc[3][2], 0, 0, 0); \
        acc[0][3] = __builtin_amdgcn_mfma_f32_16x16x32_bf16(P0, B3, acc[0][3], 0, 0, 0); \
        acc[1][3] = __builtin_amdgcn_mfma_f32_16x16x32_bf16(P1, B3, acc[1][3], 0, 0, 0); \
        acc[2][3] = __builtin_amdgcn_mfma_f32_16x16x32_bf16(P2, B3, acc[2][3], 0, 0, 0); \
        acc[3][3] = __builtin_amdgcn_mfma_f32_16x16x32_bf16(P3, B3, acc[3][3], 0, 0, 0); \
        __builtin_amdgcn_s_setprio(0);                                         \
    } while (0)

    const int nq = 2 * (it64 + 1);   // always even
    LOADSET(paA0, paA1, paA2, paA3, bxA0, bxA1, bxA2, bxA3, 0);
    for (int c = 0; c < nq; c += 2) {
        LOADSET(paB0, paB1, paB2, paB3, bxB0, bxB1, bxB2, bxB3, c + 1);
        MFMASET(paA0, paA1, paA2, paA3, bxA0, bxA1, bxA2, bxA3);
        if (c + 2 < nq)
            LOADSET(paA0, paA1, paA2, paA3, bxA0, bxA1, bxA2, bxA3, c + 2);
        MFMASET(paB0, paB1, paB2, paB3, bxB0, bxB1, bxB2, bxB3);
    }
#undef LOADSET
#undef MFMASET

    // ---- epilogue: two 32-row stages through os ----
    #pragma unroll
    for (int half = 0; half < 2; ++half) {
        if (half) __syncthreads();   // protect os reuse
        #pragma unroll
        for (int mm = 0; mm < 2; ++mm) {
            const int m = half * 2 + mm;
            #pragma unroll
            for (int r = 0; r < 4; ++r) {
                const int il = mm * 16 + lg * 4 + r;
                const float sc = linv[i0 + half * 32 + il];
                const int hl = w * 64 + lr;
                #pragma unroll
                for (int n = 0; n < 4; ++n)
                    os[il * 260 + hl + n * 16] = acc[m][n][r] * sc;
            }
        }
        __syncthreads();
        #pragma unroll
        for (int s2 = 0; s2 < 8; ++s2) {
            const int flat = s2 * 256 + tid;
            const int gi_l = flat >> 6, rm = flat & 63;
            const int gi = i0 + half * 32 + gi_l;
            float4 v;
            if (gi == 0) v = *(const float4*)&x[(size_t)t * HD + hb * 256 + rm * 4];
            else         v = *(const float4*)&os[gi_l * 260 + rm * 4];
            *(float4*)&out[((size_t)gi * TL + t) * HD + hb * 256 + rm * 4] = v;
        }
    }
}

// ---------------------------------------------------------------------------
// Fallback path (proven round-6): k_stats64 + k_pv3, used if ws too small.
// ---------------------------------------------------------------------------
__global__ __launch_bounds__(256, 4) void k_stats64(
    const unsigned short* __restrict__ qg, const unsigned short* __restrict__ kg,
    float* __restrict__ lpart)
{
    __shared__ float red[4][64];
    const int tid = threadIdx.x, lane = tid & 63, w = tid >> 6;
    const int lr = lane & 15, lg = lane >> 4;
    const int bid = blockIdx.x;
    const int lid = (bid & 7) * (2304 / 8) + (bid >> 3);
    const int it = lid % 6, t = lid / 6;
    const int i0 = it * 64;

    bf16x8 aq[4][4];
    #pragma unroll
    for (int m = 0; m < 4; ++m) {
        const unsigned short* qp = qg + ((size_t)t * NT + i0 + m * 16 + lr) * DD + lg * 8;
        #pragma unroll
        for (int kk = 0; kk < 4; ++kk) aq[m][kk] = *(const bf16x8*)(qp + kk * 32);
    }
    float psum[4][4];
    #pragma unroll
    for (int m = 0; m < 4; ++m)
        #pragma unroll
        for (int r = 0; r < 4; ++r) psum[m][r] = 0.f;

    for (int c = 0; c <= it; ++c) {
        const int j0 = c * 64;
        const unsigned short* kp = kg + ((size_t)t * NT + j0 + w * 16 + lr) * DD + lg * 8;
        bf16x8 bk8[4];
        #pragma unroll
        for (int kk = 0; kk < 4; ++kk) bk8[kk] = *(const bf16x8*)(kp + kk * 32);
        const int jg = j0 + w * 16 + lr;
        #pragma unroll
        for (int m = 0; m < 4; ++m) {
            f32x4 s = (f32x4){0.f, 0.f, 0.f, 0.f};
            #pragma unroll
            for (int kk = 0; kk < 4; ++kk)
                s = __builtin_amdgcn_mfma_f32_16x16x32_bf16(aq[m][kk], bk8[kk], s, 0, 0, 0);
            #pragma unroll
            for (int r = 0; r < 4; ++r) {
                const int ig = i0 + m * 16 + lg * 4 + r;
                psum[m][r] += (jg <= ig) ? __expf(s[r]) : 0.f;
            }
        }
    }
    #pragma unroll
    for (int off = 1; off < 16; off <<= 1)
        #pragma unroll
        for (int m = 0; m < 4; ++m)
            #pragma unroll
            for (int r = 0; r < 4; ++r)
                psum[m][r] += __shfl_xor(psum[m][r], off);
    if (lr == 0) {
        #pragma unroll
        for (int m = 0; m < 4; ++m)
            #pragma unroll
            for (int r = 0; r < 4; ++r)
                red[w][m * 16 + lg * 4 + r] = psum[m][r];
    }
    __syncthreads();
    if (tid < 64)
        lpart[(size_t)(i0 + tid) * TL + t] = red[0][tid] + red[1][tid] + red[2][tid] + red[3][tid];
}

__global__ __launch_bounds__(256, 4) void k_pv3(
    const unsigned short* __restrict__ qg, const unsigned short* __restrict__ kg,
    const unsigned short* __restrict__ xt, const float* __restrict__ linv,
    const float* __restrict__ x, float* __restrict__ out)
{
    __shared__ unsigned short P[32 * 64];
    const int tid = threadIdx.x, lane = tid & 63, w = tid >> 6;
    const int lr = lane & 15, lg = lane >> 4;
    const int bid = blockIdx.x;
    const int lid = (bid & 7) * (4608 / 8) + (bid >> 3);
    const int it = lid % 12, t = lid / 12;
    const int i0 = it * 32;
    const int h0 = blockIdx.y * 256 + w * 64;

    bf16x8 aq[2][4];
    #pragma unroll
    for (int m = 0; m < 2; ++m) {
        const unsigned short* qp = qg + ((size_t)t * NT + i0 + m * 16 + lr) * DD + lg * 8;
        #pragma unroll
        for (int kk = 0; kk < 4; ++kk) aq[m][kk] = *(const bf16x8*)(qp + kk * 32);
    }
    f32x4 acc[2][4];
    #pragma unroll
    for (int m = 0; m < 2; ++m)
        #pragma unroll
        for (int n = 0; n < 4; ++n) acc[m][n] = (f32x4){0.f, 0.f, 0.f, 0.f};

    const int nch = (i0 + 32 + 63) >> 6;
    for (int c = 0; c < nch; ++c) {
        const int j0 = c * 64;
        __syncthreads();
        f32x4 s[2] = { (f32x4){0,0,0,0}, (f32x4){0,0,0,0} };
        const unsigned short* kp = kg + ((size_t)t * NT + j0 + w * 16 + lr) * DD + lg * 8;
        #pragma unroll
        for (int kk = 0; kk < 4; ++kk) {
            const bf16x8 bk8 = *(const bf16x8*)(kp + kk * 32);
            s[0] = __builtin_amdgcn_mfma_f32_16x16x32_bf16(aq[0][kk], bk8, s[0], 0, 0, 0);
            s[1] = __builtin_amdgcn_mfma_f32_16x16x32_bf16(aq[1][kk], bk8, s[1], 0, 0, 0);
        }
        const int jg = j0 + w * 16 + lr;
        const int jl = w * 16 + lr;
        #pragma unroll
        for (int m = 0; m < 2; ++m)
            #pragma unroll
            for (int r = 0; r < 4; ++r) {
                const int il = m * 16 + lg * 4 + r;
                const float wv = (jg <= i0 + il) ? __expf(s[m][r]) : 0.f;
                P[il * 64 + (((jl >> 3) ^ (il & 7)) * 8) + (jl & 7)] = f2b(wv);
            }
        __syncthreads();
        #pragma unroll
        for (int kk2 = 0; kk2 < 2; ++kk2) {
            bf16x8 pa[2];
            #pragma unroll
            for (int m = 0; m < 2; ++m) {
                const int il = m * 16 + lr;
                const int ch = kk2 * 4 + lg;
                pa[m] = *(const bf16x8*)&P[il * 64 + ((ch ^ (il & 7)) * 8)];
            }
            const unsigned short* xp =
                xt + (((size_t)t * 12 + (j0 >> 5) + kk2) * HD + h0 + lr) * 32 + lg * 8;
            #pragma unroll
            for (int n = 0; n < 4; ++n) {
                const bf16x8 bx = *(const bf16x8*)(xp + n * 512);
                acc[0][n] = __builtin_amdgcn_mfma_f32_16x16x32_bf16(pa[0], bx, acc[0][n], 0, 0, 0);
                acc[1][n] = __builtin_amdgcn_mfma_f32_16x16x32_bf16(pa[1], bx, acc[1][n], 0, 0, 0);
            }
        }
    }
    #pragma unroll
    for (int m = 0; m < 2; ++m)
        #pragma unroll
        for (int r = 0; r < 4; ++r) {
            const int gi = i0 + m * 16 + lg * 4 + r;
            float* op = out + ((size_t)gi * TL + t) * HD + h0 + lr;
            if (gi == 0) {
                const float* xp0 = x + (size_t)t * HD + h0 + lr;
                #pragma unroll
                for (int n = 0; n < 4; ++n) op[n * 16] = xp0[n * 16];
            } else {
                const float sc = linv[gi];
                #pragma unroll
                for (int n = 0; n < 4; ++n) op[n * 16] = acc[m][n][r] * sc;
            }
        }
}

extern "C" void kernel_launch(void* const* d_in, const int* in_sizes, int n_in,
                              void* d_out, int out_size, void* d_ws, size_t ws_size,
                              hipStream_t stream)
{
    const float* x  = (const float*)d_in[0];
    const float* Wq = (const float*)d_in[1];
    const float* bq = (const float*)d_in[2];
    const float* Wk = (const float*)d_in[3];
    const float* bk = (const float*)d_in[4];
    float* out = (float*)d_out;

    unsigned short* Wt = (unsigned short*)d_ws;                 // 256*768 bf16
    unsigned short* qb = Wt + (size_t)256 * HD;                 // NT*TL*DD bf16
    unsigned short* kb = qb + (size_t)NT * TL * DD;             // NT*TL*DD bf16
    float* lpart = (float*)(kb + (size_t)NT * TL * DD);         // NT*TL f32
    float* linv  = lpart + (size_t)NT * TL;                     // NT f32
    unsigned short* xt = (unsigned short*)(linv + NT);          // TL*12*HD*32 bf16
    unsigned short* Pt = xt + (size_t)TL * 12 * HD * 32;        // TL*PT_T bf16

    const size_t need = (size_t)((char*)(Pt + (size_t)TL * PT_T) - (char*)d_ws);
    const bool use_split = ws_size >= need;

    kw_prep<<<dim3(768), 256, 0, stream>>>(Wq, Wk, Wt);
    k_proj<<<dim3(NT * TL / 64), 256, 0, stream>>>(x, Wt, bq, bk, qb, kb, xt);
    if (use_split) {
        k_qk<<<dim3(2304), 256, 0, stream>>>(qb, kb, Pt, lpart);
        k_lred<<<dim3(NT), 256, 0, stream>>>(lpart, linv);
        k_pv_g<<<dim3(6912), 256, 0, stream>>>(Pt, xt, linv, x, out);
    } else {
        k_stats64<<<dim3(2304), 256, 0, stream>>>(qb, kb, lpart);
        k_lred<<<dim3(NT), 256, 0, stream>>>(lpart, linv);
        k_pv3<<<dim3(4608, 3), 256, 0, stream>>>(qb, kb, xt, linv, x, out);
    }
}